// Round 7
// baseline (146.210 us; speedup 1.0000x reference)
//
#include <hip/hip_runtime.h>
#include <hip/hip_bf16.h>
#include <hip/hip_fp16.h>

// B=16, S=100, D=8192, P=100, W=3
constexpr int Dk   = 8192;
constexpr int Bb   = 16;
constexpr int Ss   = 100;
constexpr int Pp   = 100;
constexpr int MROW = 1632;     // 16 * 102 padded rows
constexpr int NT   = 20;       // n-tiles of 16 -> 320 cols (q|k|v|20 zero)
constexpr int NCC  = 320;
constexpr int NQ   = 304;      // reduced qkv row stride (fp32)
constexpr int KG   = 1024;     // k-groups of 8 (K=8192)
constexpr int KC   = 8;        // K splits (chunk 1024 = 32 steps of 32)
constexpr int CH   = 5;        // attn positions per block
constexpr int MBL2 = 26;       // m-blocks of 64 rows

constexpr size_t B_SEG   = (size_t)NT * KG * 128;   // shorts per B segment
constexpr size_t PSTRIDE = (size_t)1664 * NCC;      // halfs per part slice

typedef short s8v __attribute__((ext_vector_type(8)));
typedef short s4v __attribute__((ext_vector_type(4)));
typedef float f4v __attribute__((ext_vector_type(4)));

__device__ inline unsigned short f2bf_rne(float f) {
    unsigned u = __float_as_uint(f);
    u += 0x7fffu + ((u >> 16) & 1u);
    return (unsigned short)(u >> 16);
}

// async 1KB global->LDS copy: 64 lanes x 16B; LDS dest = uniform base + lane*16,
// global src = per-lane pointer (here: uniform + lane*16, matching frag layout).
__device__ inline void gl_lds16(const short* g, short* l) {
    __builtin_amdgcn_global_load_lds(
        (const __attribute__((address_space(1))) void*)g,
        (__attribute__((address_space(3))) void*)l, 16, 0, 0);
}

// Pack [wq|wk|wv|0] into hi/lo fragment layout [nt][kg][lane16][8].
__global__ __launch_bounds__(256) void pack_b(
    const float* __restrict__ wq, const float* __restrict__ wk,
    const float* __restrict__ wv,
    short* __restrict__ b_hi, short* __restrict__ b_lo) {
    const int id = blockIdx.x * 256 + threadIdx.x;
    const int n  = id % NCC;
    const int kg = id / NCC;
    if (kg >= KG) return;

    const float* w = nullptr; int p = 0;
    if (n < 100)      { w = wq; p = n; }
    else if (n < 200) { w = wk; p = n - 100; }
    else if (n < 300) { w = wv; p = n - 200; }

    s8v hi, lo;
    #pragma unroll
    for (int j = 0; j < 8; ++j) {
        const float v = w ? w[(size_t)(kg * 8 + j) * Pp + p] : 0.0f;
        const unsigned u = __float_as_uint(v);
        hi[j] = (short)(unsigned short)(u >> 16);                 // trunc split
        const float hf = __uint_as_float(u & 0xffff0000u);
        lo[j] = (short)f2bf_rne(v - hf);
    }
    const size_t doff = ((size_t)(n >> 4) * KG + kg) * 128 + (size_t)(n & 15) * 8;
    *(s8v*)(b_hi + doff) = hi;
    *(s8v*)(b_lo + doff) = lo;
}

// Fused QKV GEMM. Grid 208 (26 mb x 8 kc, XCD-pinned); 256 thr = 4 waves.
// Block tile 64(M) x 320(N); wave tile 64x80. K-chunk 1024 = 32 steps of 32.
//
// ROUND-7 RESTRUCTURE: rounds 0-6 showed a ~4000 cyc/step serial chain:
// VGPR pressure (acc 80 + B ping-pong 80 > 128) made the compiler sink the
// 10 B loads to their use point, so every step ate chunked L2 round-trips.
// Fix: B is staged via async global_load_lds into a WAVE-PRIVATE LDS ring
// (depth 2) with counted s_waitcnt vmcnt(12) -- prefetch-by-construction,
// zero VGPRs held. Lane l's frag is at src base + l*16B (kg-major layout),
// exactly the global_load_lds dest contract; ds_read_b128 back at
// base + l*16 is bank-conflict-free. Each wave stages only its own 5
// n-tiles -> no cross-wave B dependency; the per-step barrier covers A only.
// KC=8 -> 208 blocks = single residency round (1 block/CU, LDS 96KB);
// per-XCD B slice (kc=xcd) = 1.31MB, L2-resident.
//
// vmcnt ledger (per wave, batch = 10 gl_lds + 2 A loads, issued for step
// t during step t-2 AFTER that step's B ds_reads retire (lgkmcnt(0)) so
// slot reuse is WAR-safe):
//   steps 0..30: wait vmcnt(12)  (drain batch s, keep batch s+1 in flight)
//   step  31   : wait vmcnt(0)
__global__ __launch_bounds__(256, 1) void qkv_gemm(
    const float* __restrict__ x, const float* __restrict__ fpad,
    const float* __restrict__ bpad,
    const short* __restrict__ b_hi, const short* __restrict__ b_lo,
    unsigned short* __restrict__ part) {
    __shared__ __align__(16) short ahis[2][2048];        // A hi dbuf
    __shared__ __align__(16) short alos[2][2048];        // A lo dbuf
    __shared__ __align__(16) short bld[2][4][5][2][512]; // B ring [slot][wave][nt][hi/lo][1KB]

    const int id   = blockIdx.x;         // 0..207
    const int kc   = id & 7;             // dispatch round-robin -> XCD-pinned k-chunk
    const int mb   = id >> 3;            // 0..25

    const int tid  = threadIdx.x;
    const int w    = tid >> 6;           // wave 0..3 (n-slice)
    const int l    = tid & 63;
    const int m    = l & 15;
    const int quad = l >> 4;

    // A staging role: thread -> (row sr, k-group skq); 8 floats = one kg
    const int sr  = tid >> 2;            // 0..63
    const int skq = tid & 3;             // 0..3
    const float* sp;
    {
        const int r = mb * 64 + sr;
        if (r >= MROW) sp = fpad;        // junk rows, never read downstream
        else {
            const int b = r / 102, rr = r - b * 102;
            if (rr == 0)        sp = fpad + (size_t)b * Dk;
            else if (rr == 101) sp = bpad + (size_t)b * Dk;
            else                sp = x + ((size_t)b * Ss + (rr - 1)) * Dk;
        }
        sp += kc * 1024 + skq * 8;
    }
    const int woff = ((sr >> 4) * 4 + skq) * 128 + (sr & 15) * 8;

    // per-thread lane-resolved B source pointers (lane l covers bytes [16l,16l+16))
    const short *pbh[5], *pbl[5];
    #pragma unroll
    for (int j = 0; j < 5; ++j) {
        const size_t nb = ((size_t)(w * 5 + j) * KG + (size_t)kc * 128) * 128 + (size_t)l * 8;
        pbh[j] = b_hi + nb;
        pbl[j] = b_lo + nb;
    }

    // ---- prologue: issue batches 0 and 1 (B -> LDS ring, A -> reg ring) ----
    float4 av0[2], av1[2];
    #pragma unroll
    for (int t = 0; t < 2; ++t) {
        #pragma unroll
        for (int j = 0; j < 5; ++j) {
            gl_lds16(pbh[j] + (size_t)t * 512, &bld[t][w][j][0][0]);
            gl_lds16(pbl[j] + (size_t)t * 512, &bld[t][w][j][1][0]);
        }
        av0[t] = *(const float4*)(sp + t * 32);
        av1[t] = *(const float4*)(sp + t * 32 + 4);
    }

    f4v acc[4][5];
    #pragma unroll
    for (int i = 0; i < 4; ++i)
        #pragma unroll
        for (int j = 0; j < 5; ++j) {
            f4v z = {0.f, 0.f, 0.f, 0.f};
            acc[i][j] = z;
        }

#define QSTEP(S, WAITSTR, DO_ISSUE)                                            \
    {                                                                          \
        const int cur_ = (S) & 1;                                              \
        const float4 va0_ = av0[cur_], va1_ = av1[cur_];                       \
        asm volatile("s_waitcnt vmcnt(" WAITSTR ")" ::: "memory");             \
        const float vv_[8] = {va0_.x, va0_.y, va0_.z, va0_.w,                  \
                              va1_.x, va1_.y, va1_.z, va1_.w};                 \
        s8v h8_, l8_;                                                          \
        _Pragma("unroll")                                                      \
        for (int jj = 0; jj < 8; ++jj) {                                       \
            const unsigned u_ = __float_as_uint(vv_[jj]);                      \
            h8_[jj] = (short)(unsigned short)(u_ >> 16);                       \
            l8_[jj] = (short)f2bf_rne(vv_[jj] - __uint_as_float(u_ & 0xffff0000u)); \
        }                                                                      \
        *(s8v*)&ahis[cur_][woff] = h8_;                                        \
        *(s8v*)&alos[cur_][woff] = l8_;                                        \
        asm volatile("s_waitcnt lgkmcnt(0)\n\ts_barrier" ::: "memory");        \
        s8v ah_[4], al_[4], bhv_[5], blv_[5];                                  \
        _Pragma("unroll")                                                      \
        for (int i = 0; i < 4; ++i) {                                          \
            ah_[i] = *(const s8v*)&ahis[cur_][((i * 4 + quad) * 16 + m) * 8];  \
            al_[i] = *(const s8v*)&alos[cur_][((i * 4 + quad) * 16 + m) * 8];  \
        }                                                                      \
        _Pragma("unroll")                                                      \
        for (int j = 0; j < 5; ++j) {                                          \
            bhv_[j] = *(const s8v*)&bld[cur_][w][j][0][l * 8];                 \
            blv_[j] = *(const s8v*)&bld[cur_][w][j][1][l * 8];                 \
        }                                                                      \
        asm volatile("s_waitcnt lgkmcnt(0)" ::: "memory");                     \
        if (DO_ISSUE) {                                                        \
            const int t_ = (S) + 2;                                            \
            const int nc_ = t_ & 1;                                            \
            const size_t ko_ = (size_t)t_ * 512;                               \
            _Pragma("unroll")                                                  \
            for (int j = 0; j < 5; ++j) {                                      \
                gl_lds16(pbh[j] + ko_, &bld[nc_][w][j][0][0]);                 \
                gl_lds16(pbl[j] + ko_, &bld[nc_][w][j][1][0]);                 \
            }                                                                  \
            av0[nc_] = *(const float4*)(sp + t_ * 32);                         \
            av1[nc_] = *(const float4*)(sp + t_ * 32 + 4);                     \
        }                                                                      \
        _Pragma("unroll")                                                      \
        for (int j = 0; j < 5; ++j) {                                          \
            const s8v bh_ = bhv_[j], bl_ = blv_[j];                            \
            _Pragma("unroll")                                                  \
            for (int i = 0; i < 4; ++i)                                        \
                acc[i][j] = __builtin_amdgcn_mfma_f32_16x16x32_bf16(ah_[i], bh_, acc[i][j], 0, 0, 0); \
            _Pragma("unroll")                                                  \
            for (int i = 0; i < 4; ++i)                                        \
                acc[i][j] = __builtin_amdgcn_mfma_f32_16x16x32_bf16(al_[i], bh_, acc[i][j], 0, 0, 0); \
            _Pragma("unroll")                                                  \
            for (int i = 0; i < 4; ++i)                                        \
                acc[i][j] = __builtin_amdgcn_mfma_f32_16x16x32_bf16(ah_[i], bl_, acc[i][j], 0, 0, 0); \
        }                                                                      \
    }

    #pragma unroll 2
    for (int s = 0; s < 30; ++s) QSTEP(s, "12", 1)
    QSTEP(30, "12", 0)
    QSTEP(31, "0", 0)
#undef QSTEP

    // store fp16 partials, row-major [kc][row][col]
    unsigned short* __restrict__ pout = part + (size_t)kc * PSTRIDE;
    #pragma unroll
    for (int i = 0; i < 4; ++i) {
        #pragma unroll
        for (int j = 0; j < 5; ++j) {
            const int col  = (w * 5 + j) * 16 + m;
            const int row0 = mb * 64 + i * 16 + quad * 4;
            #pragma unroll
            for (int r = 0; r < 4; ++r)
                pout[(size_t)(row0 + r) * NCC + col] =
                    __half_as_ushort(__float2half(acc[i][j][r]));
        }
    }
}

// Reduce KC fp16 partial slices -> fp32 qkv (stride 304).
// Grid 260 x 256; thread = (row, 8-col group): 8x 16B loads, 2x f32x4 stores.
__global__ __launch_bounds__(256) void reduce_k(
    const unsigned short* __restrict__ part, float* __restrict__ qkv) {
    const int t = blockIdx.x * 256 + threadIdx.x;   // 0..66559
    const int row = t / 40;
    const int col0 = (t - row * 40) * 8;
    const size_t base = (size_t)row * NCC + col0;

    float sum[8] = {0.f, 0.f, 0.f, 0.f, 0.f, 0.f, 0.f, 0.f};
    #pragma unroll
    for (int k = 0; k < KC; ++k) {
        const s8v u = *(const s8v*)(part + (size_t)k * PSTRIDE + base);
        #pragma unroll
        for (int ii = 0; ii < 8; ++ii)
            sum[ii] += __half2float(__ushort_as_half((unsigned short)u[ii]));
    }
    if (col0 < NQ) {
        f4v a = {sum[0], sum[1], sum[2], sum[3]};
        f4v b = {sum[4], sum[5], sum[6], sum[7]};
        *(f4v*)(qkv + (size_t)row * NQ + col0)     = a;
        *(f4v*)(qkv + (size_t)row * NQ + col0 + 4) = b;
    }
}

// Attention on reduced fp32 qkv. Block = (b, chunk of 5 positions); grid 320.
__global__ __launch_bounds__(256) void attn3(
    const float* __restrict__ qkv, float* __restrict__ out) {
    const int blk = blockIdx.x;          // 0..319
    const int b  = blk / (Ss / CH);
    const int c  = blk % (Ss / CH);
    const int s0 = c * CH;
    const int tid = threadIdx.x;

    __shared__ float red[CH + 2][304];   // rows s0..s0+6, cols 0..299
    __shared__ float sc[CH][3];

    for (int idx = tid; idx < (CH + 2) * 300; idx += 256) {
        const int row = idx / 300, col = idx % 300;
        red[row][col] = qkv[(size_t)(b * 102 + s0 + row) * NQ + col];
    }
    __syncthreads();

    // 15 score dots, one per 16-lane group: (ss,u): Q[ss+1].K[ss+u]
    if (tid < CH * 3 * 16) {
        const int d = tid >> 4, g = tid & 15;
        const int ss = d / 3, u = d % 3;
        float ps = 0.0f;
        #pragma unroll
        for (int t = 0; t < 7; ++t) {
            const int p = g + t * 16;
            if (p < Pp) ps += red[ss + 1][p] * red[ss + u][100 + p];
        }
        #pragma unroll
        for (int off = 8; off > 0; off >>= 1) ps += __shfl_down(ps, off, 16);
        if (g == 0) sc[ss][u] = ps;
    }
    __syncthreads();

    for (int idx = tid; idx < CH * Pp; idx += 256) {
        const int ss = idx / Pp, p = idx % Pp;
        const float a0 = sc[ss][0], a1 = sc[ss][1], a2 = sc[ss][2];
        const float mx = fmaxf(a0, fmaxf(a1, a2));
        const float e0 = __expf(a0 - mx), e1 = __expf(a1 - mx), e2 = __expf(a2 - mx);
        const float inv = 1.0f / (e0 + e1 + e2);
        out[(size_t)(b * Ss + s0 + ss) * Pp + p] =
            inv * (e0 * red[ss][200 + p] + e1 * red[ss + 1][200 + p] +
                   e2 * red[ss + 2][200 + p]);
    }
}

extern "C" void kernel_launch(void* const* d_in, const int* in_sizes, int n_in,
                              void* d_out, int out_size, void* d_ws, size_t ws_size,
                              hipStream_t stream) {
    const float* x    = (const float*)d_in[0];
    const float* wq   = (const float*)d_in[1];
    const float* wk   = (const float*)d_in[2];
    const float* wv   = (const float*)d_in[3];
    const float* fpad = (const float*)d_in[4];
    const float* bpad = (const float*)d_in[5];
    float* out = (float*)d_out;

    short* b_hi = (short*)d_ws;                              // 5.24 MB
    short* b_lo = b_hi + B_SEG;                              // 5.24 MB
    unsigned short* part = (unsigned short*)(b_lo + B_SEG);  // 8*1664*320 fp16 = 8.5 MB
    float* qkv = (float*)(part + (size_t)KC * PSTRIDE);      // 1664*304 fp32 = 2.0 MB
    // total ws ~21 MB; all buffers fully overwritten, no zeroing needed

    pack_b<<<(NCC * KG) / 256, 256, 0, stream>>>(wq, wk, wv, b_hi, b_lo);
    qkv_gemm<<<MBL2 * KC, 256, 0, stream>>>(x, fpad, bpad, b_hi, b_lo, part);
    reduce_k<<<260, 256, 0, stream>>>(part, qkv);
    attn3<<<Bb * (Ss / CH), 256, 0, stream>>>(qkv, out);
}

// Round 8
// 143.862 us; speedup vs baseline: 1.0163x; 1.0163x over previous
//
#include <hip/hip_runtime.h>
#include <hip/hip_bf16.h>
#include <hip/hip_fp16.h>

// B=16, S=100, D=8192, P=100, W=3
constexpr int Dk   = 8192;
constexpr int Bb   = 16;
constexpr int Ss   = 100;
constexpr int Pp   = 100;
constexpr int MROW = 1632;     // 16 * 102 padded rows
constexpr int NT   = 20;       // n-tiles of 16 -> 320 cols (q|k|v|20 zero)
constexpr int NCC  = 320;
constexpr int NQ   = 304;      // reduced qkv row stride (fp32)
constexpr int KG   = 1024;     // k-groups of 8 (K=8192)
constexpr int KC   = 32;       // K splits (chunk 256 = 8 steps of 32)
constexpr int CH   = 5;        // attn positions per block
constexpr int MBL2 = 26;       // m-blocks of 64 rows

constexpr size_t B_SEG   = (size_t)NT * KG * 128;   // shorts per B segment
constexpr size_t PSTRIDE = (size_t)1664 * NCC;      // halfs per part slice

typedef short s8v __attribute__((ext_vector_type(8)));
typedef float f4v __attribute__((ext_vector_type(4)));

__device__ inline unsigned short f2bf_rne(float f) {
    unsigned u = __float_as_uint(f);
    u += 0x7fffu + ((u >> 16) & 1u);
    return (unsigned short)(u >> 16);
}

// Pack [wq|wk|wv|0] into hi/lo fragment layout [nt][kg][lane16][8].
__global__ __launch_bounds__(256) void pack_b(
    const float* __restrict__ wq, const float* __restrict__ wk,
    const float* __restrict__ wv,
    short* __restrict__ b_hi, short* __restrict__ b_lo) {
    const int id = blockIdx.x * 256 + threadIdx.x;
    const int n  = id % NCC;
    const int kg = id / NCC;
    if (kg >= KG) return;

    const float* w = nullptr; int p = 0;
    if (n < 100)      { w = wq; p = n; }
    else if (n < 200) { w = wk; p = n - 100; }
    else if (n < 300) { w = wv; p = n - 200; }

    s8v hi, lo;
    #pragma unroll
    for (int j = 0; j < 8; ++j) {
        const float v = w ? w[(size_t)(kg * 8 + j) * Pp + p] : 0.0f;
        const unsigned u = __float_as_uint(v);
        hi[j] = (short)(unsigned short)(u >> 16);                 // trunc split
        const float hf = __uint_as_float(u & 0xffff0000u);
        lo[j] = (short)f2bf_rne(v - hf);
    }
    const size_t doff = ((size_t)(n >> 4) * KG + kg) * 128 + (size_t)(n & 15) * 8;
    *(s8v*)(b_hi + doff) = hi;
    *(s8v*)(b_lo + doff) = lo;
}

// Fused QKV GEMM. Grid 832 (26 mb x 32 kc, XCD-pinned); 256 thr = 4 waves.
// Block tile 64(M) x 320(N); wave tile 64x80. K-chunk 256 = 8 steps of 32.
//
// ROUND-8 RESTRUCTURE: every prior variant (r0-r7: 40-52 us) shared a
// per-step s_barrier (A fp32->bf16 transpose through LDS each step) that
// locked the 4 waves into lockstep -> per-step time pinned at ~4000 cyc
// regardless of B path (reg ping-pong / async LDS ring / vmcnt ledger).
// Fix: stage the block's ENTIRE A K-chunk once up front, in MFMA fragment
// layout ([frag4][kg32][lane16][8] hi+lo = 64 KB LDS), behind ONE
// __syncthreads. The 8-step loop then has ZERO barriers: 10 B global
// loads (XCD-pinned, L2-resident) + 8 conflict-free A ds_reads
// (addr = base + s*1024 + lane*16, lane-linear) + 60 MFMAs. Waves drift
// freely; one wave's L2 stall overlaps other waves' MFMAs (2 blocks/CU
// = 8 waves). VGPR cap 256 (launch_bounds 2) gives room for a real B
// ping-pong the compiler can keep.
// A is fetched from HBM exactly once (53 MB total, each (mb,kc) tile
// distinct). B re-reads (266 MB) stay per-XCD L2-resident (kc = xcd*4+sub).
__global__ __launch_bounds__(256, 2) void qkv_gemm(
    const float* __restrict__ x, const float* __restrict__ fpad,
    const float* __restrict__ bpad,
    const short* __restrict__ b_hi, const short* __restrict__ b_lo,
    unsigned short* __restrict__ part) {
    __shared__ __align__(16) short ahi[16384];   // [frag4][kg32][lane16][8] = 32KB
    __shared__ __align__(16) short alo[16384];   // 32KB

    const int id   = blockIdx.x;         // 0..831
    const int xcd  = id & 7;             // dispatch round-robin -> XCD
    const int slot = id >> 3;            // 0..103
    const int sub  = slot & 3;           // 0..3
    const int kc   = xcd * 4 + sub;      // 0..31, pinned to this XCD
    const int mb   = slot >> 2;          // 0..25

    const int tid  = threadIdx.x;
    const int w    = tid >> 6;           // wave 0..3 (n-slice)
    const int l    = tid & 63;
    const int m    = l & 15;
    const int quad = l >> 4;

    // ---- A staging: thread -> (row sr, k-phase skq); 8 iters cover 256 k ----
    const int sr  = tid >> 2;            // 0..63
    const int skq = tid & 3;             // 0..3
    const float* sp;
    {
        const int r = mb * 64 + sr;
        if (r >= MROW) sp = fpad;        // junk rows, never read downstream
        else {
            const int b = r / 102, rr = r - b * 102;
            if (rr == 0)        sp = fpad + (size_t)b * Dk;
            else if (rr == 101) sp = bpad + (size_t)b * Dk;
            else                sp = x + ((size_t)b * Ss + (rr - 1)) * Dk;
        }
        sp += kc * 256 + skq * 8;
    }

    #pragma unroll
    for (int it = 0; it < 8; ++it) {
        const float4 v0 = *(const float4*)(sp + it * 32);
        const float4 v1 = *(const float4*)(sp + it * 32 + 4);
        const float vv[8] = {v0.x, v0.y, v0.z, v0.w, v1.x, v1.y, v1.z, v1.w};
        s8v h8, l8;
        #pragma unroll
        for (int jj = 0; jj < 8; ++jj) {
            const unsigned u = __float_as_uint(vv[jj]);
            h8[jj] = (short)(unsigned short)(u >> 16);
            l8[jj] = (short)f2bf_rne(vv[jj] - __uint_as_float(u & 0xffff0000u));
        }
        const int off = (((sr >> 4) * 32 + it * 4 + skq) * 16 + (sr & 15)) * 8;
        *(s8v*)&ahi[off] = h8;
        *(s8v*)&alo[off] = l8;
    }
    __syncthreads();     // the ONLY barrier in the kernel

    // ---- B register ping-pong, preload step 0 ----
    s8v bh[2][5], bl[2][5];
    {
        const int kg0 = kc * 32 + quad;
        #pragma unroll
        for (int j = 0; j < 5; ++j) {
            const size_t bo = ((size_t)(w * 5 + j) * KG + kg0) * 128 + (size_t)m * 8;
            bh[0][j] = *(const s8v*)(b_hi + bo);
            bl[0][j] = *(const s8v*)(b_lo + bo);
        }
    }

    f4v acc[4][5];
    #pragma unroll
    for (int i = 0; i < 4; ++i)
        #pragma unroll
        for (int j = 0; j < 5; ++j) {
            f4v z = {0.f, 0.f, 0.f, 0.f};
            acc[i][j] = z;
        }

    #pragma unroll
    for (int s = 0; s < 8; ++s) {
        const int cur = s & 1, nxt = cur ^ 1;

        // B prefetch for next step (no barrier anywhere to defeat it)
        if (s < 7) {
            const int kgn = kc * 32 + (s + 1) * 4 + quad;
            #pragma unroll
            for (int j = 0; j < 5; ++j) {
                const size_t bo = ((size_t)(w * 5 + j) * KG + kgn) * 128 + (size_t)m * 8;
                bh[nxt][j] = *(const s8v*)(b_hi + bo);
                bl[nxt][j] = *(const s8v*)(b_lo + bo);
            }
        }

        // A fragments from LDS: lane-linear, conflict-free
        s8v ah[4], al[4];
        #pragma unroll
        for (int i = 0; i < 4; ++i) {
            const int ao = ((i * 32 + s * 4 + quad) * 16 + m) * 8;
            ah[i] = *(const s8v*)&ahi[ao];
            al[i] = *(const s8v*)&alo[ao];
        }

        // 60 MFMAs
        #pragma unroll
        for (int j = 0; j < 5; ++j) {
            const s8v bhv = bh[cur][j], blv = bl[cur][j];
            #pragma unroll
            for (int i = 0; i < 4; ++i)
                acc[i][j] = __builtin_amdgcn_mfma_f32_16x16x32_bf16(ah[i], bhv, acc[i][j], 0, 0, 0);
            #pragma unroll
            for (int i = 0; i < 4; ++i)
                acc[i][j] = __builtin_amdgcn_mfma_f32_16x16x32_bf16(al[i], bhv, acc[i][j], 0, 0, 0);
            #pragma unroll
            for (int i = 0; i < 4; ++i)
                acc[i][j] = __builtin_amdgcn_mfma_f32_16x16x32_bf16(ah[i], blv, acc[i][j], 0, 0, 0);
        }
    }

    // store fp16 partials, row-major [kc][row][col]
    unsigned short* __restrict__ pout = part + (size_t)kc * PSTRIDE;
    #pragma unroll
    for (int i = 0; i < 4; ++i) {
        #pragma unroll
        for (int j = 0; j < 5; ++j) {
            const int col  = (w * 5 + j) * 16 + m;
            const int row0 = mb * 64 + i * 16 + quad * 4;
            #pragma unroll
            for (int r = 0; r < 4; ++r)
                pout[(size_t)(row0 + r) * NCC + col] =
                    __half_as_ushort(__float2half(acc[i][j][r]));
        }
    }
}

// Reduce KC fp16 partial slices -> fp32 qkv (stride 304).
// Grid 260 x 256; thread = (row, 8-col group): 32x 16B loads, 2x f32x4 stores.
__global__ __launch_bounds__(256) void reduce_k(
    const unsigned short* __restrict__ part, float* __restrict__ qkv) {
    const int t = blockIdx.x * 256 + threadIdx.x;   // 0..66559
    const int row = t / 40;
    const int col0 = (t - row * 40) * 8;
    const size_t base = (size_t)row * NCC + col0;

    float sum[8] = {0.f, 0.f, 0.f, 0.f, 0.f, 0.f, 0.f, 0.f};
    #pragma unroll
    for (int k = 0; k < KC; ++k) {
        const s8v u = *(const s8v*)(part + (size_t)k * PSTRIDE + base);
        #pragma unroll
        for (int ii = 0; ii < 8; ++ii)
            sum[ii] += __half2float(__ushort_as_half((unsigned short)u[ii]));
    }
    if (col0 < NQ) {
        f4v a = {sum[0], sum[1], sum[2], sum[3]};
        f4v b = {sum[4], sum[5], sum[6], sum[7]};
        *(f4v*)(qkv + (size_t)row * NQ + col0)     = a;
        *(f4v*)(qkv + (size_t)row * NQ + col0 + 4) = b;
    }
}

// Attention on reduced fp32 qkv. Block = (b, chunk of 5 positions); grid 320.
__global__ __launch_bounds__(256) void attn3(
    const float* __restrict__ qkv, float* __restrict__ out) {
    const int blk = blockIdx.x;          // 0..319
    const int b  = blk / (Ss / CH);
    const int c  = blk % (Ss / CH);
    const int s0 = c * CH;
    const int tid = threadIdx.x;

    __shared__ float red[CH + 2][304];   // rows s0..s0+6, cols 0..299
    __shared__ float sc[CH][3];

    for (int idx = tid; idx < (CH + 2) * 300; idx += 256) {
        const int row = idx / 300, col = idx % 300;
        red[row][col] = qkv[(size_t)(b * 102 + s0 + row) * NQ + col];
    }
    __syncthreads();

    // 15 score dots, one per 16-lane group: (ss,u): Q[ss+1].K[ss+u]
    if (tid < CH * 3 * 16) {
        const int d = tid >> 4, g = tid & 15;
        const int ss = d / 3, u = d % 3;
        float ps = 0.0f;
        #pragma unroll
        for (int t = 0; t < 7; ++t) {
            const int p = g + t * 16;
            if (p < Pp) ps += red[ss + 1][p] * red[ss + u][100 + p];
        }
        #pragma unroll
        for (int off = 8; off > 0; off >>= 1) ps += __shfl_down(ps, off, 16);
        if (g == 0) sc[ss][u] = ps;
    }
    __syncthreads();

    for (int idx = tid; idx < CH * Pp; idx += 256) {
        const int ss = idx / Pp, p = idx % Pp;
        const float a0 = sc[ss][0], a1 = sc[ss][1], a2 = sc[ss][2];
        const float mx = fmaxf(a0, fmaxf(a1, a2));
        const float e0 = __expf(a0 - mx), e1 = __expf(a1 - mx), e2 = __expf(a2 - mx);
        const float inv = 1.0f / (e0 + e1 + e2);
        out[(size_t)(b * Ss + s0 + ss) * Pp + p] =
            inv * (e0 * red[ss][200 + p] + e1 * red[ss + 1][200 + p] +
                   e2 * red[ss + 2][200 + p]);
    }
}

extern "C" void kernel_launch(void* const* d_in, const int* in_sizes, int n_in,
                              void* d_out, int out_size, void* d_ws, size_t ws_size,
                              hipStream_t stream) {
    const float* x    = (const float*)d_in[0];
    const float* wq   = (const float*)d_in[1];
    const float* wk   = (const float*)d_in[2];
    const float* wv   = (const float*)d_in[3];
    const float* fpad = (const float*)d_in[4];
    const float* bpad = (const float*)d_in[5];
    float* out = (float*)d_out;

    short* b_hi = (short*)d_ws;                              // 5.24 MB
    short* b_lo = b_hi + B_SEG;                              // 5.24 MB
    unsigned short* part = (unsigned short*)(b_lo + B_SEG);  // 32*1664*320 fp16 = 34.1 MB
    float* qkv = (float*)(part + (size_t)KC * PSTRIDE);      // 1664*304 fp32 = 2.0 MB
    // total ws ~46.6 MB; all buffers fully overwritten, no zeroing needed

    pack_b<<<(NCC * KG) / 256, 256, 0, stream>>>(wq, wk, wv, b_hi, b_lo);
    qkv_gemm<<<MBL2 * KC, 256, 0, stream>>>(x, fpad, bpad, b_hi, b_lo, part);
    reduce_k<<<260, 256, 0, stream>>>(part, qkv);
    attn3<<<Bb * (Ss / CH), 256, 0, stream>>>(qkv, out);
}

// Round 10
// 143.766 us; speedup vs baseline: 1.0170x; 1.0007x over previous
//
#include <hip/hip_runtime.h>
#include <hip/hip_bf16.h>
#include <hip/hip_fp16.h>

// B=16, S=100, D=8192, P=100, W=3
constexpr int Dk   = 8192;
constexpr int Bb   = 16;
constexpr int Ss   = 100;
constexpr int Pp   = 100;
constexpr int MROW = 1632;     // 16 * 102 padded rows
constexpr int NT   = 20;       // n-tiles of 16 -> 320 cols (q|k|v|20 zero)
constexpr int NCC  = 320;
constexpr int NQ   = 304;      // reduced qkv row stride (fp32)
constexpr int KG   = 1024;     // k-groups of 8 (K=8192)
constexpr int KC   = 32;       // K splits (chunk 256 = 8 steps of 32)
constexpr int CH   = 5;        // attn positions per block
constexpr int MBL2 = 26;       // m-blocks of 64 rows

constexpr size_t B_SEG   = (size_t)NT * KG * 128;   // shorts per B segment
constexpr size_t PSTRIDE = (size_t)1664 * NCC;      // halfs per part slice

typedef short s8v __attribute__((ext_vector_type(8)));
typedef float f4v __attribute__((ext_vector_type(4)));

__device__ inline unsigned short f2bf_rne(float f) {
    unsigned u = __float_as_uint(f);
    u += 0x7fffu + ((u >> 16) & 1u);
    return (unsigned short)(u >> 16);
}

// Pack [wq|wk|wv|0] into hi/lo fragment layout [nt][kg][lane16][8].
__global__ __launch_bounds__(256) void pack_b(
    const float* __restrict__ wq, const float* __restrict__ wk,
    const float* __restrict__ wv,
    short* __restrict__ b_hi, short* __restrict__ b_lo) {
    const int id = blockIdx.x * 256 + threadIdx.x;
    const int n  = id % NCC;
    const int kg = id / NCC;
    if (kg >= KG) return;

    const float* w = nullptr; int p = 0;
    if (n < 100)      { w = wq; p = n; }
    else if (n < 200) { w = wk; p = n - 100; }
    else if (n < 300) { w = wv; p = n - 200; }

    s8v hi, lo;
    #pragma unroll
    for (int j = 0; j < 8; ++j) {
        const float v = w ? w[(size_t)(kg * 8 + j) * Pp + p] : 0.0f;
        const unsigned u = __float_as_uint(v);
        hi[j] = (short)(unsigned short)(u >> 16);                 // trunc split
        const float hf = __uint_as_float(u & 0xffff0000u);
        lo[j] = (short)f2bf_rne(v - hf);
    }
    const size_t doff = ((size_t)(n >> 4) * KG + kg) * 128 + (size_t)(n & 15) * 8;
    *(s8v*)(b_hi + doff) = hi;
    *(s8v*)(b_lo + doff) = lo;
}

// Fused QKV GEMM. Grid 832 (26 mb x 32 kc, XCD-pinned); 256 thr = 4 waves.
// Block tile 64(M) x 320(N); wave tile 64x80. K-chunk 256 = 8 steps of 32.
//
// ROUND-10 (= round-9 resubmitted after infra failure): single-variable
// experiment on the round-8 (barrier-free) body:
// __attribute__((amdgpu_waves_per_eu(2,2))). Every variant r0-r8 pinned at
// ~4000 cyc/step with VGPR_Count <= 128: launch_bounds(,2) only sets the
// MINIMUM waves/EU, and the compiler still voluntarily targets 4 waves/EU,
// throttling pressure to 128 regs -> the B double-buffer (160 VGPR) can
// never live, so the 10 B loads/step are sunk to use -> ~5 serialized
// L3-latency chains/step. min=max=2 raises the allocator budget to 256:
// acc(80) + B ping-pong(160) + frags fit, and the unrolled, barrier-free
// step loop lets the compiler hoist each step's 10 B loads one full step
// ahead as parallel in-flight loads with counted vmcnt waits.
// Verification signal: VGPR_Count must jump to ~200-256, else void run.
// Occupancy target 2 blocks/CU (LDS 64KB x2 = 128KB <= 160KB).
__global__ __launch_bounds__(256)
__attribute__((amdgpu_waves_per_eu(2, 2))) void qkv_gemm(
    const float* __restrict__ x, const float* __restrict__ fpad,
    const float* __restrict__ bpad,
    const short* __restrict__ b_hi, const short* __restrict__ b_lo,
    unsigned short* __restrict__ part) {
    __shared__ __align__(16) short ahi[16384];   // [frag4][kg32][lane16][8] = 32KB
    __shared__ __align__(16) short alo[16384];   // 32KB

    const int id   = blockIdx.x;         // 0..831
    const int xcd  = id & 7;             // dispatch round-robin -> XCD
    const int slot = id >> 3;            // 0..103
    const int sub  = slot & 3;           // 0..3
    const int kc   = xcd * 4 + sub;      // 0..31, pinned to this XCD
    const int mb   = slot >> 2;          // 0..25

    const int tid  = threadIdx.x;
    const int w    = tid >> 6;           // wave 0..3 (n-slice)
    const int l    = tid & 63;
    const int m    = l & 15;
    const int quad = l >> 4;

    // ---- A staging: thread -> (row sr, k-phase skq); 8 iters cover 256 k ----
    const int sr  = tid >> 2;            // 0..63
    const int skq = tid & 3;             // 0..3
    const float* sp;
    {
        const int r = mb * 64 + sr;
        if (r >= MROW) sp = fpad;        // junk rows, never read downstream
        else {
            const int b = r / 102, rr = r - b * 102;
            if (rr == 0)        sp = fpad + (size_t)b * Dk;
            else if (rr == 101) sp = bpad + (size_t)b * Dk;
            else                sp = x + ((size_t)b * Ss + (rr - 1)) * Dk;
        }
        sp += kc * 256 + skq * 8;
    }

    #pragma unroll
    for (int it = 0; it < 8; ++it) {
        const float4 v0 = *(const float4*)(sp + it * 32);
        const float4 v1 = *(const float4*)(sp + it * 32 + 4);
        const float vv[8] = {v0.x, v0.y, v0.z, v0.w, v1.x, v1.y, v1.z, v1.w};
        s8v h8, l8;
        #pragma unroll
        for (int jj = 0; jj < 8; ++jj) {
            const unsigned u = __float_as_uint(vv[jj]);
            h8[jj] = (short)(unsigned short)(u >> 16);
            l8[jj] = (short)f2bf_rne(vv[jj] - __uint_as_float(u & 0xffff0000u));
        }
        const int off = (((sr >> 4) * 32 + it * 4 + skq) * 16 + (sr & 15)) * 8;
        *(s8v*)&ahi[off] = h8;
        *(s8v*)&alo[off] = l8;
    }
    __syncthreads();     // the ONLY barrier in the kernel

    // ---- B register ping-pong, preload step 0 ----
    s8v bh[2][5], bl[2][5];
    {
        const int kg0 = kc * 32 + quad;
        #pragma unroll
        for (int j = 0; j < 5; ++j) {
            const size_t bo = ((size_t)(w * 5 + j) * KG + kg0) * 128 + (size_t)m * 8;
            bh[0][j] = *(const s8v*)(b_hi + bo);
            bl[0][j] = *(const s8v*)(b_lo + bo);
        }
    }

    f4v acc[4][5];
    #pragma unroll
    for (int i = 0; i < 4; ++i)
        #pragma unroll
        for (int j = 0; j < 5; ++j) {
            f4v z = {0.f, 0.f, 0.f, 0.f};
            acc[i][j] = z;
        }

    #pragma unroll
    for (int s = 0; s < 8; ++s) {
        const int cur = s & 1, nxt = cur ^ 1;

        // B prefetch for next step (no barrier anywhere to defeat it)
        if (s < 7) {
            const int kgn = kc * 32 + (s + 1) * 4 + quad;
            #pragma unroll
            for (int j = 0; j < 5; ++j) {
                const size_t bo = ((size_t)(w * 5 + j) * KG + kgn) * 128 + (size_t)m * 8;
                bh[nxt][j] = *(const s8v*)(b_hi + bo);
                bl[nxt][j] = *(const s8v*)(b_lo + bo);
            }
        }

        // A fragments from LDS: lane-linear, conflict-free
        s8v ah[4], al[4];
        #pragma unroll
        for (int i = 0; i < 4; ++i) {
            const int ao = ((i * 32 + s * 4 + quad) * 16 + m) * 8;
            ah[i] = *(const s8v*)&ahi[ao];
            al[i] = *(const s8v*)&alo[ao];
        }

        // 60 MFMAs
        #pragma unroll
        for (int j = 0; j < 5; ++j) {
            const s8v bhv = bh[cur][j], blv = bl[cur][j];
            #pragma unroll
            for (int i = 0; i < 4; ++i)
                acc[i][j] = __builtin_amdgcn_mfma_f32_16x16x32_bf16(ah[i], bhv, acc[i][j], 0, 0, 0);
            #pragma unroll
            for (int i = 0; i < 4; ++i)
                acc[i][j] = __builtin_amdgcn_mfma_f32_16x16x32_bf16(al[i], bhv, acc[i][j], 0, 0, 0);
            #pragma unroll
            for (int i = 0; i < 4; ++i)
                acc[i][j] = __builtin_amdgcn_mfma_f32_16x16x32_bf16(ah[i], blv, acc[i][j], 0, 0, 0);
        }
    }

    // store fp16 partials, row-major [kc][row][col]
    unsigned short* __restrict__ pout = part + (size_t)kc * PSTRIDE;
    #pragma unroll
    for (int i = 0; i < 4; ++i) {
        #pragma unroll
        for (int j = 0; j < 5; ++j) {
            const int col  = (w * 5 + j) * 16 + m;
            const int row0 = mb * 64 + i * 16 + quad * 4;
            #pragma unroll
            for (int r = 0; r < 4; ++r)
                pout[(size_t)(row0 + r) * NCC + col] =
                    __half_as_ushort(__float2half(acc[i][j][r]));
        }
    }
}

// Reduce KC fp16 partial slices -> fp32 qkv (stride 304).
// Grid 260 x 256; thread = (row, 8-col group): 32x 16B loads, 2x f32x4 stores.
__global__ __launch_bounds__(256) void reduce_k(
    const unsigned short* __restrict__ part, float* __restrict__ qkv) {
    const int t = blockIdx.x * 256 + threadIdx.x;   // 0..66559
    const int row = t / 40;
    const int col0 = (t - row * 40) * 8;
    const size_t base = (size_t)row * NCC + col0;

    float sum[8] = {0.f, 0.f, 0.f, 0.f, 0.f, 0.f, 0.f, 0.f};
    #pragma unroll
    for (int k = 0; k < KC; ++k) {
        const s8v u = *(const s8v*)(part + (size_t)k * PSTRIDE + base);
        #pragma unroll
        for (int ii = 0; ii < 8; ++ii)
            sum[ii] += __half2float(__ushort_as_half((unsigned short)u[ii]));
    }
    if (col0 < NQ) {
        f4v a = {sum[0], sum[1], sum[2], sum[3]};
        f4v b = {sum[4], sum[5], sum[6], sum[7]};
        *(f4v*)(qkv + (size_t)row * NQ + col0)     = a;
        *(f4v*)(qkv + (size_t)row * NQ + col0 + 4) = b;
    }
}

// Attention on reduced fp32 qkv. Block = (b, chunk of 5 positions); grid 320.
__global__ __launch_bounds__(256) void attn3(
    const float* __restrict__ qkv, float* __restrict__ out) {
    const int blk = blockIdx.x;          // 0..319
    const int b  = blk / (Ss / CH);
    const int c  = blk % (Ss / CH);
    const int s0 = c * CH;
    const int tid = threadIdx.x;

    __shared__ float red[CH + 2][304];   // rows s0..s0+6, cols 0..299
    __shared__ float sc[CH][3];

    for (int idx = tid; idx < (CH + 2) * 300; idx += 256) {
        const int row = idx / 300, col = idx % 300;
        red[row][col] = qkv[(size_t)(b * 102 + s0 + row) * NQ + col];
    }
    __syncthreads();

    // 15 score dots, one per 16-lane group: (ss,u): Q[ss+1].K[ss+u]
    if (tid < CH * 3 * 16) {
        const int d = tid >> 4, g = tid & 15;
        const int ss = d / 3, u = d % 3;
        float ps = 0.0f;
        #pragma unroll
        for (int t = 0; t < 7; ++t) {
            const int p = g + t * 16;
            if (p < Pp) ps += red[ss + 1][p] * red[ss + u][100 + p];
        }
        #pragma unroll
        for (int off = 8; off > 0; off >>= 1) ps += __shfl_down(ps, off, 16);
        if (g == 0) sc[ss][u] = ps;
    }
    __syncthreads();

    for (int idx = tid; idx < CH * Pp; idx += 256) {
        const int ss = idx / Pp, p = idx % Pp;
        const float a0 = sc[ss][0], a1 = sc[ss][1], a2 = sc[ss][2];
        const float mx = fmaxf(a0, fmaxf(a1, a2));
        const float e0 = __expf(a0 - mx), e1 = __expf(a1 - mx), e2 = __expf(a2 - mx);
        const float inv = 1.0f / (e0 + e1 + e2);
        out[(size_t)(b * Ss + s0 + ss) * Pp + p] =
            inv * (e0 * red[ss][200 + p] + e1 * red[ss + 1][200 + p] +
                   e2 * red[ss + 2][200 + p]);
    }
}

extern "C" void kernel_launch(void* const* d_in, const int* in_sizes, int n_in,
                              void* d_out, int out_size, void* d_ws, size_t ws_size,
                              hipStream_t stream) {
    const float* x    = (const float*)d_in[0];
    const float* wq   = (const float*)d_in[1];
    const float* wk   = (const float*)d_in[2];
    const float* wv   = (const float*)d_in[3];
    const float* fpad = (const float*)d_in[4];
    const float* bpad = (const float*)d_in[5];
    float* out = (float*)d_out;

    short* b_hi = (short*)d_ws;                              // 5.24 MB
    short* b_lo = b_hi + B_SEG;                              // 5.24 MB
    unsigned short* part = (unsigned short*)(b_lo + B_SEG);  // 32*1664*320 fp16 = 34.1 MB
    float* qkv = (float*)(part + (size_t)KC * PSTRIDE);      // 1664*304 fp32 = 2.0 MB
    // total ws ~46.6 MB; all buffers fully overwritten, no zeroing needed

    pack_b<<<(NCC * KG) / 256, 256, 0, stream>>>(wq, wk, wv, b_hi, b_lo);
    qkv_gemm<<<MBL2 * KC, 256, 0, stream>>>(x, fpad, bpad, b_hi, b_lo, part);
    reduce_k<<<260, 256, 0, stream>>>(part, qkv);
    attn3<<<Bb * (Ss / CH), 256, 0, stream>>>(qkv, out);
}

// Round 11
// 137.218 us; speedup vs baseline: 1.0655x; 1.0477x over previous
//
#include <hip/hip_runtime.h>
#include <hip/hip_bf16.h>
#include <hip/hip_fp16.h>

// B=16, S=100, D=8192, P=100, W=3
constexpr int Dk   = 8192;
constexpr int Bb   = 16;
constexpr int Ss   = 100;
constexpr int Pp   = 100;
constexpr int MROW = 1632;     // 16 * 102 padded rows
constexpr int NT   = 20;       // n-tiles of 16 -> 320 cols (q|k|v|20 zero)
constexpr int NCC  = 320;
constexpr int NQ   = 304;      // reduced qkv row stride (fp32)
constexpr int KG   = 1024;     // k-groups of 8 (K=8192)
constexpr int KC   = 16;       // K splits (chunk 512 = 16 steps of 32)
constexpr int CH   = 5;        // attn positions per block
constexpr int MBL3 = 13;       // m-blocks of 128 rows

constexpr size_t B_SEG   = (size_t)NT * KG * 128;   // shorts per B segment
constexpr size_t PSTRIDE = (size_t)1664 * NCC;      // halfs per part slice

typedef short s8v __attribute__((ext_vector_type(8)));
typedef float f4v __attribute__((ext_vector_type(4)));

__device__ inline unsigned short f2bf_rne(float f) {
    unsigned u = __float_as_uint(f);
    u += 0x7fffu + ((u >> 16) & 1u);
    return (unsigned short)(u >> 16);
}

// Pack [wq|wk|wv|0] into hi/lo fragment layout [nt][kg][lane16][8].
__global__ __launch_bounds__(256) void pack_b(
    const float* __restrict__ wq, const float* __restrict__ wk,
    const float* __restrict__ wv,
    short* __restrict__ b_hi, short* __restrict__ b_lo) {
    const int id = blockIdx.x * 256 + threadIdx.x;
    const int n  = id % NCC;
    const int kg = id / NCC;
    if (kg >= KG) return;

    const float* w = nullptr; int p = 0;
    if (n < 100)      { w = wq; p = n; }
    else if (n < 200) { w = wk; p = n - 100; }
    else if (n < 300) { w = wv; p = n - 200; }

    s8v hi, lo;
    #pragma unroll
    for (int j = 0; j < 8; ++j) {
        const float v = w ? w[(size_t)(kg * 8 + j) * Pp + p] : 0.0f;
        const unsigned u = __float_as_uint(v);
        hi[j] = (short)(unsigned short)(u >> 16);                 // trunc split
        const float hf = __uint_as_float(u & 0xffff0000u);
        lo[j] = (short)f2bf_rne(v - hf);
    }
    const size_t doff = ((size_t)(n >> 4) * KG + kg) * 128 + (size_t)(n & 15) * 8;
    *(s8v*)(b_hi + doff) = hi;
    *(s8v*)(b_lo + doff) = lo;
}

// Fused QKV GEMM. Grid 208 (13 mb x 16 kc, XCD-pinned); 512 thr = 8 waves.
// Block tile 128(M) x 320(N); wave grid 2(M) x 4(N), wave tile 64x80.
// K-chunk 512, staged in two halves of 256; 8 MFMA steps of 32 per half.
//
// ROUND-11 STRUCTURE: force the register budget via launch shape.
// r0-r10 all pinned at VGPR<=128 (compiler targets 4 waves/SIMD when the
// launch shape permits it) -> B double-buffer (80 VGPR) + acc (80) + A
// frags (32) never fit -> B loads sunk to use -> ~4000 cyc/step serial
// L2/L3 latency chains. Here 512 threads + 128 KB LDS pin occupancy to
// 1 block/CU = 2 waves/SIMD STRUCTURALLY, so the allocator budget is 256
// VGPRs and the ~192-reg working set fits. Gate: VGPR_Count >= 180.
// Bonus: BM=128 halves B L2 traffic (133 MB), 8 waves/CU = 2x independent
// load streams, and 208 blocks = ONE residency round (no tail rounds).
// Barriers: 3 per kernel (publish half0, drain half0 reads, publish half1),
// not per-step.
__global__ __launch_bounds__(512) void qkv_gemm(
    const float* __restrict__ x, const float* __restrict__ fpad,
    const float* __restrict__ bpad,
    const short* __restrict__ b_hi, const short* __restrict__ b_lo,
    unsigned short* __restrict__ part) {
    __shared__ __align__(16) short ahi[32768];   // [frag8][kg32][lane16][8] = 64KB
    __shared__ __align__(16) short alo[32768];   // 64KB

    const int id   = blockIdx.x;         // 0..207
    const int xcd  = id & 7;             // dispatch round-robin -> XCD
    const int slot = id >> 3;            // 0..25
    const int sub  = slot & 1;           // 0..1
    const int kc   = xcd * 2 + sub;      // 0..15, pinned to this XCD
    const int mb   = slot >> 1;          // 0..12

    const int tid  = threadIdx.x;        // 0..511
    const int w    = tid >> 6;           // wave 0..7
    const int wm   = w >> 2;             // m-half 0..1
    const int wn   = w & 3;              // n-quarter 0..3
    const int l    = tid & 63;
    const int m    = l & 15;
    const int quad = l >> 4;

    // ---- A staging role: thread -> (row sr 0..127, k-phase skq 0..3) ----
    const int sr  = tid >> 2;
    const int skq = tid & 3;
    const float* sp;
    {
        const int r = mb * 128 + sr;
        if (r >= MROW) sp = fpad;        // junk rows, never read downstream
        else {
            const int b = r / 102, rr = r - b * 102;
            if (rr == 0)        sp = fpad + (size_t)b * Dk;
            else if (rr == 101) sp = bpad + (size_t)b * Dk;
            else                sp = x + ((size_t)b * Ss + (rr - 1)) * Dk;
        }
        sp += kc * 512 + skq * 8;
    }
    const int wbase = ((sr >> 4) * 32 + skq) * 16 + (sr & 15);   // +it*4*16 per iter

    // stage one K=256 half (h = 0/1) into ahi/alo
    auto stage_half = [&](int h) {
        #pragma unroll
        for (int it = 0; it < 8; ++it) {
            const float4 v0 = *(const float4*)(sp + h * 256 + it * 32);
            const float4 v1 = *(const float4*)(sp + h * 256 + it * 32 + 4);
            const float vv[8] = {v0.x, v0.y, v0.z, v0.w, v1.x, v1.y, v1.z, v1.w};
            s8v h8, l8;
            #pragma unroll
            for (int jj = 0; jj < 8; ++jj) {
                const unsigned u = __float_as_uint(vv[jj]);
                h8[jj] = (short)(unsigned short)(u >> 16);
                l8[jj] = (short)f2bf_rne(vv[jj] - __uint_as_float(u & 0xffff0000u));
            }
            const int off = (wbase + it * 64) * 8;   // (frag*32 + it*4 + skq) rows of 16 lanes
            *(s8v*)&ahi[off] = h8;
            *(s8v*)&alo[off] = l8;
        }
    };

    stage_half(0);
    asm volatile("s_waitcnt lgkmcnt(0)\n\ts_barrier" ::: "memory");  // publish half 0

    // ---- B register ping-pong, preload step 0 ----
    s8v bh[2][5], bl[2][5];
    {
        const int kg0 = kc * 64 + quad;
        #pragma unroll
        for (int j = 0; j < 5; ++j) {
            const size_t bo = ((size_t)(wn * 5 + j) * KG + kg0) * 128 + (size_t)m * 8;
            bh[0][j] = *(const s8v*)(b_hi + bo);
            bl[0][j] = *(const s8v*)(b_lo + bo);
        }
    }

    f4v acc[4][5];
    #pragma unroll
    for (int i = 0; i < 4; ++i)
        #pragma unroll
        for (int j = 0; j < 5; ++j) {
            f4v z = {0.f, 0.f, 0.f, 0.f};
            acc[i][j] = z;
        }

    #pragma unroll
    for (int h = 0; h < 2; ++h) {
        #pragma unroll
        for (int s = 0; s < 8; ++s) {
            const int t   = h * 8 + s;       // linear step 0..15
            const int cur = t & 1, nxt = cur ^ 1;

            // B prefetch for next step (crosses the half boundary freely)
            if (t < 15) {
                const int tn = t + 1;
                const int kgn = kc * 64 + (tn >> 3) * 32 + (tn & 7) * 4 + quad;
                #pragma unroll
                for (int j = 0; j < 5; ++j) {
                    const size_t bo = ((size_t)(wn * 5 + j) * KG + kgn) * 128 + (size_t)m * 8;
                    bh[nxt][j] = *(const s8v*)(b_hi + bo);
                    bl[nxt][j] = *(const s8v*)(b_lo + bo);
                }
            }

            // A fragments from LDS: lane-linear, conflict-free
            s8v ah[4], al[4];
            #pragma unroll
            for (int i = 0; i < 4; ++i) {
                const int ao = (((wm * 4 + i) * 32 + s * 4 + quad) * 16 + m) * 8;
                ah[i] = *(const s8v*)&ahi[ao];
                al[i] = *(const s8v*)&alo[ao];
            }

            // 60 MFMAs
            #pragma unroll
            for (int j = 0; j < 5; ++j) {
                const s8v bhv = bh[cur][j], blv = bl[cur][j];
                #pragma unroll
                for (int i = 0; i < 4; ++i)
                    acc[i][j] = __builtin_amdgcn_mfma_f32_16x16x32_bf16(ah[i], bhv, acc[i][j], 0, 0, 0);
                #pragma unroll
                for (int i = 0; i < 4; ++i)
                    acc[i][j] = __builtin_amdgcn_mfma_f32_16x16x32_bf16(al[i], bhv, acc[i][j], 0, 0, 0);
                #pragma unroll
                for (int i = 0; i < 4; ++i)
                    acc[i][j] = __builtin_amdgcn_mfma_f32_16x16x32_bf16(ah[i], blv, acc[i][j], 0, 0, 0);
            }
        }
        if (h == 0) {
            // all waves done READING half 0 before overwrite, then publish half 1
            asm volatile("s_waitcnt lgkmcnt(0)\n\ts_barrier" ::: "memory");
            stage_half(1);
            asm volatile("s_waitcnt lgkmcnt(0)\n\ts_barrier" ::: "memory");
        }
    }

    // store fp16 partials, row-major [kc][row][col]
    unsigned short* __restrict__ pout = part + (size_t)kc * PSTRIDE;
    #pragma unroll
    for (int i = 0; i < 4; ++i) {
        #pragma unroll
        for (int j = 0; j < 5; ++j) {
            const int col  = (wn * 5 + j) * 16 + m;
            const int row0 = mb * 128 + (wm * 4 + i) * 16 + quad * 4;
            #pragma unroll
            for (int r = 0; r < 4; ++r)
                pout[(size_t)(row0 + r) * NCC + col] =
                    __half_as_ushort(__float2half(acc[i][j][r]));
        }
    }
}

// Reduce KC fp16 partial slices -> fp32 qkv (stride 304).
// Grid 260 x 256; thread = (row, 8-col group): 16x 16B loads, 2x f32x4 stores.
__global__ __launch_bounds__(256) void reduce_k(
    const unsigned short* __restrict__ part, float* __restrict__ qkv) {
    const int t = blockIdx.x * 256 + threadIdx.x;   // 0..66559
    const int row = t / 40;
    const int col0 = (t - row * 40) * 8;
    const size_t base = (size_t)row * NCC + col0;

    float sum[8] = {0.f, 0.f, 0.f, 0.f, 0.f, 0.f, 0.f, 0.f};
    #pragma unroll
    for (int k = 0; k < KC; ++k) {
        const s8v u = *(const s8v*)(part + (size_t)k * PSTRIDE + base);
        #pragma unroll
        for (int ii = 0; ii < 8; ++ii)
            sum[ii] += __half2float(__ushort_as_half((unsigned short)u[ii]));
    }
    if (col0 < NQ) {
        f4v a = {sum[0], sum[1], sum[2], sum[3]};
        f4v b = {sum[4], sum[5], sum[6], sum[7]};
        *(f4v*)(qkv + (size_t)row * NQ + col0)     = a;
        *(f4v*)(qkv + (size_t)row * NQ + col0 + 4) = b;
    }
}

// Attention on reduced fp32 qkv. Block = (b, chunk of 5 positions); grid 320.
__global__ __launch_bounds__(256) void attn3(
    const float* __restrict__ qkv, float* __restrict__ out) {
    const int blk = blockIdx.x;          // 0..319
    const int b  = blk / (Ss / CH);
    const int c  = blk % (Ss / CH);
    const int s0 = c * CH;
    const int tid = threadIdx.x;

    __shared__ float red[CH + 2][304];   // rows s0..s0+6, cols 0..299
    __shared__ float sc[CH][3];

    for (int idx = tid; idx < (CH + 2) * 300; idx += 256) {
        const int row = idx / 300, col = idx % 300;
        red[row][col] = qkv[(size_t)(b * 102 + s0 + row) * NQ + col];
    }
    __syncthreads();

    // 15 score dots, one per 16-lane group: (ss,u): Q[ss+1].K[ss+u]
    if (tid < CH * 3 * 16) {
        const int d = tid >> 4, g = tid & 15;
        const int ss = d / 3, u = d % 3;
        float ps = 0.0f;
        #pragma unroll
        for (int t = 0; t < 7; ++t) {
            const int p = g + t * 16;
            if (p < Pp) ps += red[ss + 1][p] * red[ss + u][100 + p];
        }
        #pragma unroll
        for (int off = 8; off > 0; off >>= 1) ps += __shfl_down(ps, off, 16);
        if (g == 0) sc[ss][u] = ps;
    }
    __syncthreads();

    for (int idx = tid; idx < CH * Pp; idx += 256) {
        const int ss = idx / Pp, p = idx % Pp;
        const float a0 = sc[ss][0], a1 = sc[ss][1], a2 = sc[ss][2];
        const float mx = fmaxf(a0, fmaxf(a1, a2));
        const float e0 = __expf(a0 - mx), e1 = __expf(a1 - mx), e2 = __expf(a2 - mx);
        const float inv = 1.0f / (e0 + e1 + e2);
        out[(size_t)(b * Ss + s0 + ss) * Pp + p] =
            inv * (e0 * red[ss][200 + p] + e1 * red[ss + 1][200 + p] +
                   e2 * red[ss + 2][200 + p]);
    }
}

extern "C" void kernel_launch(void* const* d_in, const int* in_sizes, int n_in,
                              void* d_out, int out_size, void* d_ws, size_t ws_size,
                              hipStream_t stream) {
    const float* x    = (const float*)d_in[0];
    const float* wq   = (const float*)d_in[1];
    const float* wk   = (const float*)d_in[2];
    const float* wv   = (const float*)d_in[3];
    const float* fpad = (const float*)d_in[4];
    const float* bpad = (const float*)d_in[5];
    float* out = (float*)d_out;

    short* b_hi = (short*)d_ws;                              // 5.24 MB
    short* b_lo = b_hi + B_SEG;                              // 5.24 MB
    unsigned short* part = (unsigned short*)(b_lo + B_SEG);  // 16*1664*320 fp16 = 17.0 MB
    float* qkv = (float*)(part + (size_t)KC * PSTRIDE);      // 1664*304 fp32 = 2.0 MB
    // total ws ~29.6 MB; all buffers fully overwritten, no zeroing needed

    pack_b<<<(NCC * KG) / 256, 256, 0, stream>>>(wq, wk, wv, b_hi, b_lo);
    qkv_gemm<<<MBL3 * KC, 512, 0, stream>>>(x, fpad, bpad, b_hi, b_lo, part);
    reduce_k<<<260, 256, 0, stream>>>(part, qkv);
    attn3<<<Bb * (Ss / CH), 256, 0, stream>>>(qkv, out);
}